// Round 3
// baseline (505.564 us; speedup 1.0000x reference)
//
#include <hip/hip_runtime.h>

// Problem constants
// B=16, CI=CO=32, H=W=256, K0=K1=M=32, KAPPA=8, NPARA=7
// Kept modes: ky rows j in [0,64): ky = j (j<32) or j-64 (j>=32, i.e. rows 224..255)
//             kx cols 0..31
//
// Pipeline (raw/unnormalized DFTs; total 1/65536 ortho factor folded into Ftab):
//  K0: Ftab[col][w], col=2k   -> c_k*cos(2*pi*k*w/256)/65536
//                     col=2k+1 -> -c_k*sin(...)/65536,  c_0=1, c_k=2
//  K1: Xw[row][kx]  = sum_w x[row][w] * e^{-2*pi*i*kx*w/256}         (row = (b,ci,h))
//  K2: Xf[p][j][kx] = sum_h Xw[p*256+h][kx] * e^{-2*pi*i*ky_j*h/256} (p = b*32+ci)
//  K3: Ff[q][j][kx] = sum_ci Xf * (W + s_b*We)    (q = b*32+co; corner-specific W/We)
//  K4: G[h][kx] = sum_j Ff * e^{+2*pi*i*ky_j*h/256};  out[h][w] = sum_col Gt*Ftab

__global__ void k_ftab(float* __restrict__ Ftab) {
    const int w = threadIdx.x;      // 0..255
    const int col = blockIdx.x;     // 0..63
    const int k = col >> 1, ri = col & 1;
    const float sk = (k == 0 ? 1.0f : 2.0f) / 65536.0f;
    float sv, cv;
    sincospif(2.0f * k * w / 256.0f, &sv, &cv);
    Ftab[col * 256 + w] = (ri == 0) ? sk * cv : -sk * sv;
}

// K1: row DFT. Block handles 64 rows; thread (g=tid>>5, kx=tid&31) does 8 rows for one kx.
__global__ __launch_bounds__(256) void k_rowdft(const float* __restrict__ x,
                                                float* __restrict__ Xw) {
    __shared__ __align__(16) float xs[64 * 256];  // 64 KB
    const int tid = threadIdx.x;
    const long rowbase = (long)blockIdx.x * 64;

    const float4* src = (const float4*)(x + rowbase * 256);
    float4* dst4 = (float4*)xs;
#pragma unroll
    for (int m = 0; m < 16; ++m) dst4[m * 256 + tid] = src[m * 256 + tid];
    __syncthreads();

    const int kx = tid & 31, g = tid >> 5;
    float sc, ss;
    sincospif(kx / 128.0f, &ss, &sc);  // theta = 2*pi*kx/256
    ss = -ss;                          // step = e^{-i*theta}
    float c = 1.0f, s = 0.0f;          // rot = e^{-i*theta*w}
    float accr[8] = {0}, acci[8] = {0};
    const float4* xs4 = (const float4*)xs;

    for (int w4 = 0; w4 < 64; ++w4) {
        float4 xv[8];
#pragma unroll
        for (int i = 0; i < 8; ++i) xv[i] = xs4[(g * 8 + i) * 64 + w4];
#pragma unroll
        for (int jw = 0; jw < 4; ++jw) {
#pragma unroll
            for (int i = 0; i < 8; ++i) {
                const float xvv = (&xv[i].x)[jw];
                accr[i] = fmaf(xvv, c, accr[i]);
                acci[i] = fmaf(xvv, s, acci[i]);
            }
            const float cn = c * sc - s * ss;
            s = s * sc + c * ss;
            c = cn;
        }
    }
#pragma unroll
    for (int i = 0; i < 8; ++i) {
        const long r = rowbase + g * 8 + i;
        ((float2*)(Xw + r * 64))[kx] = make_float2(accr[i], acci[i]);
    }
}

// K2: column DFT per (b,ci). Thread (ja=tid>>3, kxg=tid&7): j in {ja, ja+32}, kx = kxg*4..+3.
__global__ __launch_bounds__(256) void k_coldft(const float* __restrict__ Xw,
                                                float* __restrict__ Xf) {
    __shared__ __align__(16) float xs[256 * 64];  // [h][kx*2], 64 KB
    const int tid = threadIdx.x;
    const long p = blockIdx.x;  // b*32+ci

    const float4* src = (const float4*)(Xw + p * 16384);
    float4* dst4 = (float4*)xs;
#pragma unroll
    for (int m = 0; m < 16; ++m) dst4[m * 256 + tid] = src[m * 256 + tid];
    __syncthreads();

    const int ja = tid >> 3, kxg = tid & 7;
    float sca, ssa, scb, ssb;
    sincospif(ja / 128.0f, &ssa, &sca);          // ky_a = ja
    ssa = -ssa;
    sincospif((ja - 32) / 128.0f, &ssb, &scb);   // ky_b = ja - 32  (rows 224..255)
    ssb = -ssb;
    float ca = 1.0f, sa = 0.0f, cb = 1.0f, sb = 0.0f;
    float ar[2][4] = {{0}}, ai[2][4] = {{0}};
    const float4* xs4 = (const float4*)xs;

    for (int h = 0; h < 256; ++h) {
        const float4 u = xs4[h * 16 + kxg * 2];
        const float4 v = xs4[h * 16 + kxg * 2 + 1];
        const float xr[4] = {u.x, u.z, v.x, v.z};
        const float xi[4] = {u.y, u.w, v.y, v.w};
#pragma unroll
        for (int m = 0; m < 4; ++m) {
            ar[0][m] += xr[m] * ca - xi[m] * sa;
            ai[0][m] += xr[m] * sa + xi[m] * ca;
            ar[1][m] += xr[m] * cb - xi[m] * sb;
            ai[1][m] += xr[m] * sb + xi[m] * cb;
        }
        float t;
        t = ca * sca - sa * ssa; sa = sa * sca + ca * ssa; ca = t;
        t = cb * scb - sb * ssb; sb = sb * scb + cb * ssb; cb = t;
    }
#pragma unroll
    for (int jj = 0; jj < 2; ++jj) {
        const int j = ja + jj * 32;
        float4* o = (float4*)(Xf + ((p * 64 + j) * 32 + kxg * 4) * 2);
        o[0] = make_float4(ar[jj][0], ai[jj][0], ar[jj][1], ai[jj][1]);
        o[1] = make_float4(ar[jj][2], ai[jj][2], ar[jj][3], ai[jj][3]);
    }
}

// K3: mode mixing. Block per (j,kx): Ff[q][j][kx] = sum_ci Xf[p][j][kx]*(W + s_b*We)
// NOTE: Xf/Ff are indexed with the FULL j (0..63); weights/scaling with jj = j&31.
__global__ __launch_bounds__(256) void k_mix(const float* __restrict__ Xf,
                                             const float* __restrict__ fs,
                                             const float* __restrict__ w0,
                                             const float* __restrict__ w1,
                                             const float* __restrict__ we0,
                                             const float* __restrict__ we1,
                                             float* __restrict__ Ff) {
    __shared__ float2 xv[512];    // [b*32+ci]
    __shared__ float2 wsw[1024];  // [ci*32+co]
    __shared__ float2 wse[1024];
    __shared__ float sv[16];
    const int tid = threadIdx.x;
    const int j = blockIdx.x >> 5, kx = blockIdx.x & 31;
    const int jj = j & 31;
    const float* W = (j < 32) ? w0 : w1;
    const float* We = (j < 32) ? we0 : we1;
    const int moff = (jj * 32 + kx) * 2;  // weight offset (per-corner row index)
    const int foff = (j * 32 + kx) * 2;   // spectrum offset (full j)

    for (int t = tid; t < 512; t += 256)
        xv[t] = *(const float2*)(Xf + (long)t * 4096 + foff);
    for (int t = tid; t < 1024; t += 256) {
        wsw[t] = *(const float2*)(W + (long)t * 2048 + moff);
        wse[t] = *(const float2*)(We + (long)t * 2048 + moff);
    }
    if (tid < 16) {
        // hierarchical quadrant index of (u=jj, v=kx); KAPPA=8, LEVEL0=3
        const int u = jj, v = kx;
        int idx;
        if (u < 8 && v < 8) idx = 0;
        else if (u < 16 && v < 16) idx = (u < 8) ? 1 : ((v < 8) ? 2 : 3);
        else idx = (u < 16) ? 4 : ((v < 16) ? 5 : 6);
        sv[tid] = fs[tid * 7 + idx];
    }
    __syncthreads();

    for (int t = tid; t < 512; t += 256) {
        const int b = t >> 5, co = t & 31;
        const float s = sv[b];
        float re = 0.0f, im = 0.0f;
#pragma unroll 8
        for (int ci = 0; ci < 32; ++ci) {
            const float2 xc = xv[b * 32 + ci];
            const float2 wc = wsw[ci * 32 + co];
            const float2 ec = wse[ci * 32 + co];
            const float mr = wc.x + s * ec.x;
            const float mi = wc.y + s * ec.y;
            re += xc.x * mr - xc.y * mi;
            im += xc.x * mi + xc.y * mr;
        }
        *(float2*)(Ff + (long)t * 4096 + foff) = make_float2(re, im);
    }
}

// K4: fused inverse. Block per (q = b*32+co, h-half of 128 rows).
__global__ __launch_bounds__(256) void k_inv(const float* __restrict__ Ff,
                                             const float* __restrict__ Ftab,
                                             float* __restrict__ out) {
    __shared__ __align__(16) float Fs[4096];      // [j][kx][2], 16 KB
    __shared__ __align__(16) float Gt[64 * 132];  // [col][hh], padded, 33 KB
    const int tid = threadIdx.x;
    const long q = blockIdx.x >> 1;
    const int hbase = (blockIdx.x & 1) * 128;

    {
        const float4* src = (const float4*)(Ff + q * 4096);
        float4* dst = (float4*)Fs;
#pragma unroll
        for (int m = 0; m < 4; ++m) dst[m * 256 + tid] = src[m * 256 + tid];
    }
    __syncthreads();

    // Phase B: G[h][kx] = sum_j F[j][kx] * e^{+2*pi*i*ky_j*h/256}
    {
        const int hg = tid >> 3, kxg = tid & 7;
        const int h0 = hbase + hg * 4;
        float gr[4][4] = {}, gi[4][4] = {};
        float stc[4], sts[4], rc[4], rs[4];
#pragma unroll
        for (int i = 0; i < 4; ++i) {
            sincospif((h0 + i) / 128.0f, &sts[i], &stc[i]);  // step e^{+2*pi*i*h/256}
            rc[i] = 1.0f; rs[i] = 0.0f;
        }
        const float4* Fs4 = (const float4*)Fs;
        for (int j = 0; j < 64; ++j) {
            if (j == 32) {
#pragma unroll
                for (int i = 0; i < 4; ++i)  // rot = e^{-i*pi*h/4} (ky jumps to -32)
                    sincospif(-((h0 + i) & 7) / 4.0f, &rs[i], &rc[i]);
            }
            // Fs row j = 64 floats = 16 float4s
            const float4 u = Fs4[j * 16 + kxg * 2];
            const float4 v = Fs4[j * 16 + kxg * 2 + 1];
            const float fr[4] = {u.x, u.z, v.x, v.z};
            const float fi[4] = {u.y, u.w, v.y, v.w};
#pragma unroll
            for (int i = 0; i < 4; ++i) {
#pragma unroll
                for (int m = 0; m < 4; ++m) {
                    gr[i][m] += fr[m] * rc[i] - fi[m] * rs[i];
                    gi[i][m] += fr[m] * rs[i] + fi[m] * rc[i];
                }
                const float t = rc[i] * stc[i] - rs[i] * sts[i];
                rs[i] = rs[i] * stc[i] + rc[i] * sts[i];
                rc[i] = t;
            }
        }
#pragma unroll
        for (int m = 0; m < 4; ++m) {
            const int col = (kxg * 4 + m) * 2;
            *(float4*)(Gt + col * 132 + hg * 4) =
                make_float4(gr[0][m], gr[1][m], gr[2][m], gr[3][m]);
            *(float4*)(Gt + (col + 1) * 132 + hg * 4) =
                make_float4(gi[0][m], gi[1][m], gi[2][m], gi[3][m]);
        }
    }
    __syncthreads();

    // Phase C: out[h][w] = sum_col Gt[col][hh] * Ftab[col][w]
    {
        const int ht = tid >> 4, wt = tid & 15;
#pragma unroll
        for (int wq = 0; wq < 4; ++wq) {
            const int w0 = wq * 64 + wt * 4;
            float acc[8][4] = {};
            for (int k = 0; k < 64; ++k) {
                const float4 g0 = *(const float4*)(Gt + k * 132 + ht * 8);
                const float4 g1 = *(const float4*)(Gt + k * 132 + ht * 8 + 4);
                const float4 f = *(const float4*)(Ftab + k * 256 + w0);
                const float gv[8] = {g0.x, g0.y, g0.z, g0.w, g1.x, g1.y, g1.z, g1.w};
#pragma unroll
                for (int i = 0; i < 8; ++i) {
                    acc[i][0] += gv[i] * f.x;
                    acc[i][1] += gv[i] * f.y;
                    acc[i][2] += gv[i] * f.z;
                    acc[i][3] += gv[i] * f.w;
                }
            }
#pragma unroll
            for (int i = 0; i < 8; ++i) {
                const int h = hbase + ht * 8 + i;
                *(float4*)(out + q * 65536 + (long)h * 256 + w0) =
                    make_float4(acc[i][0], acc[i][1], acc[i][2], acc[i][3]);
            }
        }
    }
}

extern "C" void kernel_launch(void* const* d_in, const int* in_sizes, int n_in,
                              void* d_out, int out_size, void* d_ws, size_t ws_size,
                              hipStream_t stream) {
    (void)in_sizes; (void)n_in; (void)out_size; (void)ws_size;
    const float* x   = (const float*)d_in[0];
    const float* fs  = (const float*)d_in[1];
    const float* w0  = (const float*)d_in[2];
    const float* w1  = (const float*)d_in[3];
    const float* we0 = (const float*)d_in[4];
    const float* we1 = (const float*)d_in[5];
    float* out = (float*)d_out;
    float* ws = (float*)d_ws;

    float* Ftab = ws;                  // 16384 floats
    float* Xw   = ws + 16384;          // 8388608 floats [row][kx][2]
    float* Xf   = Xw + 8388608;        // 2097152 floats [p][j][kx][2]
    float* Ff   = Xf + 2097152;        // 2097152 floats [q][j][kx][2]

    k_ftab  <<<64,   256, 0, stream>>>(Ftab);
    k_rowdft<<<2048, 256, 0, stream>>>(x, Xw);
    k_coldft<<<512,  256, 0, stream>>>(Xw, Xf);
    k_mix   <<<2048, 256, 0, stream>>>(Xf, fs, w0, w1, we0, we1, Ff);
    k_inv   <<<1024, 256, 0, stream>>>(Ff, Ftab, out);
}